// Round 19
// baseline (213.422 us; speedup 1.0000x reference)
//
#include <hip/hip_runtime.h>
#include <hip/hip_bf16.h>
#include <float.h>

#define C 64
#define H 4
#define HC 256
#define NEG_SLOPE 0.2f
#define EPS_SEG 1e-16f
#define LN_EPS 1e-5f
#define LDSP 528  // LDS tile pitch: 512B row + 16B bank-spread pad

typedef __attribute__((ext_vector_type(8))) short bf16x8;
typedef __attribute__((ext_vector_type(4))) float f32x4;

__device__ __forceinline__ float warp_sum(float v) {
#pragma unroll
    for (int m = 32; m >= 1; m >>= 1) v += __shfl_xor(v, m, 64);
    return v;
}

__device__ __forceinline__ unsigned short f2bf(float f) {
    unsigned int u = __float_as_uint(f);
    return (unsigned short)((u + 0x7FFF + ((u >> 16) & 1)) >> 16);  // RNE
}
__device__ __forceinline__ float bf2f(unsigned short u) {
    return __uint_as_float(((unsigned int)u) << 16);
}

// ---------------- CSR build (once per call; graph is layer-invariant) -------

__global__ void k_zero(int* __restrict__ a, int n) {
    int i = blockIdx.x * blockDim.x + threadIdx.x;
    int stride = gridDim.x * blockDim.x;
    for (int j = i; j < n; j += stride) a[j] = 0;
}

__global__ void k_count(const int* __restrict__ ei, int* __restrict__ counts,
                        int E, int Etot) {
    int eid = blockIdx.x * blockDim.x + threadIdx.x;
    if (eid >= Etot) return;
    int d = (eid < E) ? ei[E + eid] : eid - E;
    atomicAdd(&counts[d], 1);
}

__global__ __launch_bounds__(256) void k_scan1(const int* __restrict__ counts,
                                               int* __restrict__ tmp,
                                               int* __restrict__ bsum, int N) {
    __shared__ int sm[256];
    int t = threadIdx.x;
    int i = blockIdx.x * 256 + t;
    sm[t] = (i < N) ? counts[i] : 0;
    __syncthreads();
    for (int off = 1; off < 256; off <<= 1) {
        int add = (t >= off) ? sm[t - off] : 0;
        __syncthreads();
        sm[t] += add;
        __syncthreads();
    }
    if (i < N) tmp[i] = sm[t];
    if (t == 255) bsum[blockIdx.x] = sm[255];
}

__global__ __launch_bounds__(256) void k_scan2(int* __restrict__ bsum, int nb) {
    __shared__ int sm[256];
    int t = threadIdx.x;
    sm[t] = (t < nb) ? bsum[t] : 0;
    __syncthreads();
    for (int off = 1; off < 256; off <<= 1) {
        int add = (t >= off) ? sm[t - off] : 0;
        __syncthreads();
        sm[t] += add;
        __syncthreads();
    }
    if (t < nb) bsum[t] = (t > 0) ? sm[t - 1] : 0;  // exclusive
}

__global__ __launch_bounds__(256) void k_scan3(const int* __restrict__ tmp,
                                               const int* __restrict__ boff,
                                               int* __restrict__ rowptr,
                                               int* __restrict__ cursor, int N) {
    int i = blockIdx.x * 256 + threadIdx.x;
    if (i < N) {
        rowptr[i + 1] = tmp[i] + boff[blockIdx.x];
        cursor[i] = 0;
    }
    if (i == 0) rowptr[0] = 0;
}

__global__ void k_fill(const int* __restrict__ ei, const int* __restrict__ rowptr,
                       int* __restrict__ cursor, int* __restrict__ col,
                       int E, int Etot) {
    int eid = blockIdx.x * blockDim.x + threadIdx.x;
    if (eid >= Etot) return;
    int s, d;
    if (eid < E) { s = ei[eid]; d = ei[E + eid]; } else { s = d = eid - E; }
    int pos = rowptr[d] + atomicAdd(&cursor[d], 1);
    col[pos] = s;
}

// ---------------- per-layer kernels ----------------------------------------

// f32 [N][C] -> bf16 [Npad][C] (pad rows zeroed); layer-0 only.
__global__ void k_prep_x(const float4* __restrict__ xin, ushort4* __restrict__ xb,
                         int n4, int npad4) {
    int i = blockIdx.x * blockDim.x + threadIdx.x;
    int st = gridDim.x * blockDim.x;
    for (int j = i; j < npad4; j += st) {
        ushort4 o;
        if (j < n4) {
            float4 v = xin[j];
            o.x = f2bf(v.x); o.y = f2bf(v.y); o.z = f2bf(v.z); o.w = f2bf(v.w);
        } else {
            o.x = o.y = o.z = o.w = 0;
        }
        xb[j] = o;
    }
}

// All weight transposes (Wg + W1 + W2, both layers) in one launch.
__global__ void k_prep_weights(const float* __restrict__ Wg,
                               const float* __restrict__ W1, const float* __restrict__ W2,
                               unsigned short* __restrict__ Wgt,
                               unsigned short* __restrict__ W1t,
                               unsigned short* __restrict__ W2t, int L) {
    int i = blockIdx.x * 256 + threadIdx.x;
    int nWg = L * C * HC;
    int nW = L * C * C;
    if (i < nWg) {
        int l = i / (C * HC);
        int r = i - l * C * HC;
        int n = r >> 6, k = r & 63;
        Wgt[(size_t)l * HC * C + n * C + k] = f2bf(Wg[(size_t)l * C * HC + k * HC + n]);
    } else if (i < nWg + nW) {
        int j = i - nWg;
        int l = j / (C * C);
        int r = j - l * C * C;
        int n = r >> 6, k = r & 63;
        W1t[(size_t)l * C * C + n * C + k] = f2bf(W1[(size_t)l * C * C + k * C + n]);
        W2t[(size_t)l * C * C + n * C + k] = f2bf(W2[(size_t)l * C * C + k * C + n]);
    }
}

// xh = xb @ Wg via MFMA (layer-0 only). D staged through LDS for coalesced
// dwordx4 xh stores. Scores to dense Npad-sized s_src/s_dst (L2-resident).
__global__ __launch_bounds__(256) void k_gemm_mfma(
    const unsigned short* __restrict__ xb, const unsigned short* __restrict__ Wgt,
    const float* __restrict__ a_src, const float* __restrict__ a_dst,
    unsigned short* __restrict__ xh, float* __restrict__ s_src,
    float* __restrict__ s_dst, int N)
{
    __shared__ char tile[64 * LDSP];  // 33 KB
    int w = threadIdx.x >> 6, l = threadIdx.x & 63;
    int n0 = blockIdx.x * 64;
    int lr = l & 15, q = l >> 4, lk = q * 8;
    bf16x8 bfr[4][2];
    float as[4], ad[4];
#pragma unroll
    for (int ct = 0; ct < 4; ct++) {
        int colg = w * 64 + ct * 16 + lr;
#pragma unroll
        for (int ks = 0; ks < 2; ks++)
            bfr[ct][ks] = *reinterpret_cast<const bf16x8*>(Wgt + colg * C + ks * 32 + lk);
        as[ct] = a_src[w * C + ct * 16 + lr];
        ad[ct] = a_dst[w * C + ct * 16 + lr];
    }
#pragma unroll
    for (int rt = 0; rt < 4; rt++) {
        const unsigned short* arow = xb + (size_t)(n0 + rt * 16 + lr) * C + lk;
        bf16x8 a0 = *reinterpret_cast<const bf16x8*>(arow);
        bf16x8 a1 = *reinterpret_cast<const bf16x8*>(arow + 32);
        f32x4 acc[4];
#pragma unroll
        for (int ct = 0; ct < 4; ct++) {
            acc[ct] = (f32x4){0.f, 0.f, 0.f, 0.f};
            acc[ct] = __builtin_amdgcn_mfma_f32_16x16x32_bf16(a0, bfr[ct][0], acc[ct], 0, 0, 0);
            acc[ct] = __builtin_amdgcn_mfma_f32_16x16x32_bf16(a1, bfr[ct][1], acc[ct], 0, 0, 0);
        }
        int rowl = rt * 16 + q * 4;
#pragma unroll
        for (int ct = 0; ct < 4; ct++) {
            int cb = (w * 64 + ct * 16 + lr) * 2;
#pragma unroll
            for (int r = 0; r < 4; r++)
                *(unsigned short*)(tile + (rowl + r) * LDSP + cb) = f2bf(acc[ct][r]);
        }
#pragma unroll
        for (int r = 0; r < 4; r++) {
            float ps = acc[0][r] * as[0] + acc[1][r] * as[1]
                     + acc[2][r] * as[2] + acc[3][r] * as[3];
            float pd = acc[0][r] * ad[0] + acc[1][r] * ad[1]
                     + acc[2][r] * ad[2] + acc[3][r] * ad[3];
#pragma unroll
            for (int off = 1; off < 16; off <<= 1) {
                ps += __shfl_xor(ps, off, 64);
                pd += __shfl_xor(pd, off, 64);
            }
            if (lr == 0) {
                int n = n0 + rowl + r;  // < Npad; buffers Npad-sized
                s_src[(size_t)n * H + w] = ps;
                s_dst[(size_t)n * H + w] = pd;
            }
        }
    }
    __syncthreads();
#pragma unroll
    for (int it = 0; it < 8; it++) {
        int off = threadIdx.x * 16 + it * 4096;
        int row = off >> 9;
        int cin = off & 511;
        uint4 v = *(const uint4*)(tile + row * LDSP + cin);
        *(uint4*)((char*)xh + (size_t)(n0 + row) * 512 + cin) = v;
    }
}

// One wave per destination node; lane l = h*16+gq. MLP-4 chunk loop +
// 3-slot tail; dense 512B xh rows; scores from compact L2-resident arrays.
// Output: bf16 x1b ONLY (FFN takes residual from bf16 too).
__global__ __launch_bounds__(256) void k_gat_node(
    const int* __restrict__ rowptr, const int* __restrict__ col,
    const float* __restrict__ s_src, const float* __restrict__ s_dst,
    const unsigned short* __restrict__ xh,
    const float* __restrict__ x_in, const float* __restrict__ bias,
    const float* __restrict__ g, const float* __restrict__ b,
    unsigned short* __restrict__ x1b, int N)
{
    int n = (blockIdx.x * blockDim.x + threadIdx.x) >> 6;
    int l = threadIdx.x & 63;
    int h = l >> 4, gq = l & 15;
    if (n >= N) return;
    int r0 = rowptr[n], r1 = rowptr[n + 1];

    float4 xi = *(const float4*)(x_in + (size_t)n * C + gq * 4);
    float4 bia = *(const float4*)(bias + gq * 4);
    float sdh = s_dst[n * H + h];

    const char* xbase = (const char*)xh;
    int laneoff = h * 128 + gq * 8;

    float a0 = 0.f, a1 = 0.f, a2 = 0.f, a3 = 0.f, z = 0.f;

    int j = r0;
    for (; j + 4 <= r1; j += 4) {
        int s0 = col[j], s1 = col[j + 1], s2 = col[j + 2], s3 = col[j + 3];
        uint2 v0 = *(const uint2*)(xbase + (size_t)s0 * 512 + laneoff);
        uint2 v1 = *(const uint2*)(xbase + (size_t)s1 * 512 + laneoff);
        uint2 v2 = *(const uint2*)(xbase + (size_t)s2 * 512 + laneoff);
        uint2 v3 = *(const uint2*)(xbase + (size_t)s3 * 512 + laneoff);
        float e0 = s_src[s0 * H + h] + sdh;
        float e1 = s_src[s1 * H + h] + sdh;
        float e2 = s_src[s2 * H + h] + sdh;
        float e3 = s_src[s3 * H + h] + sdh;
        float w0 = __expf(fmaxf(e0, NEG_SLOPE * e0));
        float w1 = __expf(fmaxf(e1, NEG_SLOPE * e1));
        float w2 = __expf(fmaxf(e2, NEG_SLOPE * e2));
        float w3 = __expf(fmaxf(e3, NEG_SLOPE * e3));
        a0 += w0 * __uint_as_float(v0.x << 16);
        a1 += w0 * __uint_as_float(v0.x & 0xFFFF0000u);
        a2 += w0 * __uint_as_float(v0.y << 16);
        a3 += w0 * __uint_as_float(v0.y & 0xFFFF0000u);
        a0 += w1 * __uint_as_float(v1.x << 16);
        a1 += w1 * __uint_as_float(v1.x & 0xFFFF0000u);
        a2 += w1 * __uint_as_float(v1.y << 16);
        a3 += w1 * __uint_as_float(v1.y & 0xFFFF0000u);
        a0 += w2 * __uint_as_float(v2.x << 16);
        a1 += w2 * __uint_as_float(v2.x & 0xFFFF0000u);
        a2 += w2 * __uint_as_float(v2.y << 16);
        a3 += w2 * __uint_as_float(v2.y & 0xFFFF0000u);
        a0 += w3 * __uint_as_float(v3.x << 16);
        a1 += w3 * __uint_as_float(v3.x & 0xFFFF0000u);
        a2 += w3 * __uint_as_float(v3.y << 16);
        a3 += w3 * __uint_as_float(v3.y & 0xFFFF0000u);
        z += w0 + w1 + w2 + w3;
    }
    {   // tail (0-3 edges): masked weights, wave-uniform predication
        int t = r1 - j;
        int s0 = 0, s1 = 0, s2 = 0;
        if (t > 0) s0 = col[j];
        if (t > 1) s1 = col[j + 1];
        if (t > 2) s2 = col[j + 2];
        uint2 v0 = {0, 0}, v1 = {0, 0}, v2 = {0, 0};
        float e0 = 0.f, e1 = 0.f, e2 = 0.f;
        if (t > 0) { v0 = *(const uint2*)(xbase + (size_t)s0 * 512 + laneoff); e0 = s_src[s0 * H + h] + sdh; }
        if (t > 1) { v1 = *(const uint2*)(xbase + (size_t)s1 * 512 + laneoff); e1 = s_src[s1 * H + h] + sdh; }
        if (t > 2) { v2 = *(const uint2*)(xbase + (size_t)s2 * 512 + laneoff); e2 = s_src[s2 * H + h] + sdh; }
        float w0 = (t > 0) ? __expf(fmaxf(e0, NEG_SLOPE * e0)) : 0.f;
        float w1 = (t > 1) ? __expf(fmaxf(e1, NEG_SLOPE * e1)) : 0.f;
        float w2 = (t > 2) ? __expf(fmaxf(e2, NEG_SLOPE * e2)) : 0.f;
        a0 += w0 * __uint_as_float(v0.x << 16);
        a1 += w0 * __uint_as_float(v0.x & 0xFFFF0000u);
        a2 += w0 * __uint_as_float(v0.y << 16);
        a3 += w0 * __uint_as_float(v0.y & 0xFFFF0000u);
        a0 += w1 * __uint_as_float(v1.x << 16);
        a1 += w1 * __uint_as_float(v1.x & 0xFFFF0000u);
        a2 += w1 * __uint_as_float(v1.y << 16);
        a3 += w1 * __uint_as_float(v1.y & 0xFFFF0000u);
        a0 += w2 * __uint_as_float(v2.x << 16);
        a1 += w2 * __uint_as_float(v2.x & 0xFFFF0000u);
        a2 += w2 * __uint_as_float(v2.y << 16);
        a3 += w2 * __uint_as_float(v2.y & 0xFFFF0000u);
        z += w0 + w1 + w2;
    }

    float inv = 0.25f / (z + EPS_SEG);
    a0 *= inv; a1 *= inv; a2 *= inv; a3 *= inv;
#pragma unroll
    for (int off = 16; off <= 32; off <<= 1) {
        a0 += __shfl_xor(a0, off, 64);
        a1 += __shfl_xor(a1, off, 64);
        a2 += __shfl_xor(a2, off, 64);
        a3 += __shfl_xor(a3, off, 64);
    }
    float y0 = xi.x + a0 + bia.x;
    float y1 = xi.y + a1 + bia.y;
    float y2 = xi.z + a2 + bia.z;
    float y3 = xi.w + a3 + bia.w;
    float mu = warp_sum(y0 + y1 + y2 + y3) * (1.f / (C * 4));
    float d0 = y0 - mu, d1 = y1 - mu, d2 = y2 - mu, d3 = y3 - mu;
    float var = warp_sum(d0 * d0 + d1 * d1 + d2 * d2 + d3 * d3) * (1.f / (C * 4));
    float rs = rsqrtf(var + LN_EPS);
    if (h == 0) {
        float4 gg = *(const float4*)(g + gq * 4);
        float4 bb = *(const float4*)(b + gq * 4);
        ushort4 ob;
        ob.x = f2bf(d0 * rs * gg.x + bb.x);
        ob.y = f2bf(d1 * rs * gg.y + bb.y);
        ob.z = f2bf(d2 * rs * gg.z + bb.z);
        ob.w = f2bf(d3 * rs * gg.w + bb.w);
        *(ushort4*)(x1b + (size_t)n * C + gq * 4) = ob;
    }
}

// FFN + residual + LN (standalone; LAST layer). Residual from bf16 x1b.
__global__ __launch_bounds__(256) void k_ffn_mfma(
    const unsigned short* __restrict__ x1b,
    const unsigned short* __restrict__ W1t, const unsigned short* __restrict__ W2t,
    const float* __restrict__ b1, const float* __restrict__ b2,
    const float* __restrict__ g, const float* __restrict__ b,
    float* __restrict__ xout, int N)
{
    __shared__ unsigned short hls[64 * 64];  // 8 KB
    int w = threadIdx.x >> 6, l = threadIdx.x & 63;
    int lr = l & 15, q = l >> 4, lk = q * 8;
    int n0 = blockIdx.x * 64;

    {
        bf16x8 bf[4][2];
#pragma unroll
        for (int ct = 0; ct < 4; ct++)
#pragma unroll
            for (int ks = 0; ks < 2; ks++)
                bf[ct][ks] = *reinterpret_cast<const bf16x8*>(
                    W1t + (ct * 16 + lr) * C + ks * 32 + lk);
        const unsigned short* arow = x1b + (size_t)(n0 + w * 16 + lr) * C + lk;
        bf16x8 a0 = *reinterpret_cast<const bf16x8*>(arow);
        bf16x8 a1 = *reinterpret_cast<const bf16x8*>(arow + 32);
        f32x4 acc[4];
#pragma unroll
        for (int ct = 0; ct < 4; ct++) {
            acc[ct] = (f32x4){0.f, 0.f, 0.f, 0.f};
            acc[ct] = __builtin_amdgcn_mfma_f32_16x16x32_bf16(a0, bf[ct][0], acc[ct], 0, 0, 0);
            acc[ct] = __builtin_amdgcn_mfma_f32_16x16x32_bf16(a1, bf[ct][1], acc[ct], 0, 0, 0);
        }
#pragma unroll
        for (int ct = 0; ct < 4; ct++) {
            float bc = b1[ct * 16 + lr];
#pragma unroll
            for (int r = 0; r < 4; r++) {
                float v = fmaxf(acc[ct][r] + bc, 0.f);
                int rowb = w * 16 + q * 4 + r;
                int byte = (rowb * 128 + (ct * 16 + lr) * 2) ^ ((rowb & 7) << 4);
                *(unsigned short*)((char*)hls + byte) = f2bf(v);
            }
        }
    }
    __syncthreads();

    bf16x8 bf[4][2];
#pragma unroll
    for (int ct = 0; ct < 4; ct++)
#pragma unroll
        for (int ks = 0; ks < 2; ks++)
            bf[ct][ks] = *reinterpret_cast<const bf16x8*>(
                W2t + (ct * 16 + lr) * C + ks * 32 + lk);
    bf16x8 h0, h1;
    {
        int rowb = w * 16 + lr;
        int swz = (rowb & 7) << 4;
        h0 = *(bf16x8*)((char*)hls + ((rowb * 128 + q * 16) ^ swz));
        h1 = *(bf16x8*)((char*)hls + ((rowb * 128 + 64 + q * 16) ^ swz));
    }
    f32x4 acc[4];
#pragma unroll
    for (int ct = 0; ct < 4; ct++) {
        acc[ct] = (f32x4){0.f, 0.f, 0.f, 0.f};
        acc[ct] = __builtin_amdgcn_mfma_f32_16x16x32_bf16(h0, bf[ct][0], acc[ct], 0, 0, 0);
        acc[ct] = __builtin_amdgcn_mfma_f32_16x16x32_bf16(h1, bf[ct][1], acc[ct], 0, 0, 0);
    }

    float b2c[4], gc[4], bc[4];
#pragma unroll
    for (int ct = 0; ct < 4; ct++) {
        int cg = ct * 16 + lr;
        b2c[ct] = b2[cg]; gc[ct] = g[cg]; bc[ct] = b[cg];
    }
    float yv[4][4];
#pragma unroll
    for (int r = 0; r < 4; r++) {
        int n = n0 + w * 16 + q * 4 + r;
        bool ok = n < N;
#pragma unroll
        for (int ct = 0; ct < 4; ct++) {
            float xr = ok ? bf2f(x1b[(size_t)n * C + ct * 16 + lr]) : 0.f;
            yv[ct][r] = acc[ct][r] + b2c[ct] + xr;
        }
    }
#pragma unroll
    for (int r = 0; r < 4; r++) {
        int n = n0 + w * 16 + q * 4 + r;
        float s = yv[0][r] + yv[1][r] + yv[2][r] + yv[3][r];
#pragma unroll
        for (int off = 1; off < 16; off <<= 1) s += __shfl_xor(s, off, 64);
        float mu = s * (1.f / C);
        float d0 = yv[0][r] - mu, d1 = yv[1][r] - mu;
        float d2 = yv[2][r] - mu, d3 = yv[3][r] - mu;
        float vs = d0 * d0 + d1 * d1 + d2 * d2 + d3 * d3;
#pragma unroll
        for (int off = 1; off < 16; off <<= 1) vs += __shfl_xor(vs, off, 64);
        float rs = rsqrtf(vs * (1.f / C) + LN_EPS);
        if (n < N) {
            float dd[4] = {d0, d1, d2, d3};
#pragma unroll
            for (int ct = 0; ct < 4; ct++) {
                float o = dd[ct] * rs * gc[ct] + bc[ct];
                xout[(size_t)n * C + ct * 16 + lr] = o;
            }
        }
    }
}

// FUSED: FFN(layer l) + GEMM(layer l+1); residual from bf16 x1b; y-tile
// stays in LDS and feeds the next layer's xh = y @ Wg MFMA + scores.
__global__ __launch_bounds__(256) void k_ffn_gemm(
    const unsigned short* __restrict__ x1b,
    const unsigned short* __restrict__ W1t, const unsigned short* __restrict__ W2t,
    const float* __restrict__ b1, const float* __restrict__ b2,
    const float* __restrict__ g, const float* __restrict__ b,
    const unsigned short* __restrict__ Wgt2,
    const float* __restrict__ a_src2, const float* __restrict__ a_dst2,
    float* __restrict__ xout, unsigned short* __restrict__ xh,
    float* __restrict__ s_src, float* __restrict__ s_dst, int N)
{
    __shared__ char tile[64 * LDSP];         // 33 KB xh staging
    __shared__ unsigned short hls[64 * 64];  // 8 KB: h-tile, then y-tile
    int w = threadIdx.x >> 6, l = threadIdx.x & 63;
    int lr = l & 15, q = l >> 4, lk = q * 8;
    int n0 = blockIdx.x * 64;

    // ---- FFN phase 1: h = relu(x1 @ W1 + b1) -> hls ----
    {
        bf16x8 bf[4][2];
#pragma unroll
        for (int ct = 0; ct < 4; ct++)
#pragma unroll
            for (int ks = 0; ks < 2; ks++)
                bf[ct][ks] = *reinterpret_cast<const bf16x8*>(
                    W1t + (ct * 16 + lr) * C + ks * 32 + lk);
        const unsigned short* arow = x1b + (size_t)(n0 + w * 16 + lr) * C + lk;
        bf16x8 a0 = *reinterpret_cast<const bf16x8*>(arow);
        bf16x8 a1 = *reinterpret_cast<const bf16x8*>(arow + 32);
        f32x4 acc[4];
#pragma unroll
        for (int ct = 0; ct < 4; ct++) {
            acc[ct] = (f32x4){0.f, 0.f, 0.f, 0.f};
            acc[ct] = __builtin_amdgcn_mfma_f32_16x16x32_bf16(a0, bf[ct][0], acc[ct], 0, 0, 0);
            acc[ct] = __builtin_amdgcn_mfma_f32_16x16x32_bf16(a1, bf[ct][1], acc[ct], 0, 0, 0);
        }
#pragma unroll
        for (int ct = 0; ct < 4; ct++) {
            float bc = b1[ct * 16 + lr];
#pragma unroll
            for (int r = 0; r < 4; r++) {
                float v = fmaxf(acc[ct][r] + bc, 0.f);
                int rowb = w * 16 + q * 4 + r;
                int byte = (rowb * 128 + (ct * 16 + lr) * 2) ^ ((rowb & 7) << 4);
                *(unsigned short*)((char*)hls + byte) = f2bf(v);
            }
        }
    }
    __syncthreads();

    // ---- FFN phase 2: y = h @ W2 + b2 + x1, LN -> xout f32 + y bf16 in hls --
    {
        bf16x8 bf[4][2];
#pragma unroll
        for (int ct = 0; ct < 4; ct++)
#pragma unroll
            for (int ks = 0; ks < 2; ks++)
                bf[ct][ks] = *reinterpret_cast<const bf16x8*>(
                    W2t + (ct * 16 + lr) * C + ks * 32 + lk);
        bf16x8 h0, h1;
        {
            int rowb = w * 16 + lr;
            int swz = (rowb & 7) << 4;
            h0 = *(bf16x8*)((char*)hls + ((rowb * 128 + q * 16) ^ swz));
            h1 = *(bf16x8*)((char*)hls + ((rowb * 128 + 64 + q * 16) ^ swz));
        }
        __syncthreads();  // all h reads complete before hls is overwritten
        f32x4 acc[4];
#pragma unroll
        for (int ct = 0; ct < 4; ct++) {
            acc[ct] = (f32x4){0.f, 0.f, 0.f, 0.f};
            acc[ct] = __builtin_amdgcn_mfma_f32_16x16x32_bf16(h0, bf[ct][0], acc[ct], 0, 0, 0);
            acc[ct] = __builtin_amdgcn_mfma_f32_16x16x32_bf16(h1, bf[ct][1], acc[ct], 0, 0, 0);
        }
        float b2c[4], gc[4], bc[4];
#pragma unroll
        for (int ct = 0; ct < 4; ct++) {
            int cg = ct * 16 + lr;
            b2c[ct] = b2[cg]; gc[ct] = g[cg]; bc[ct] = b[cg];
        }
        float yv[4][4];
#pragma unroll
        for (int r = 0; r < 4; r++) {
            int n = n0 + w * 16 + q * 4 + r;
            bool ok = n < N;
#pragma unroll
            for (int ct = 0; ct < 4; ct++) {
                float xr = ok ? bf2f(x1b[(size_t)n * C + ct * 16 + lr]) : 0.f;
                yv[ct][r] = acc[ct][r] + b2c[ct] + xr;
            }
        }
#pragma unroll
        for (int r = 0; r < 4; r++) {
            int rowb = w * 16 + q * 4 + r;
            int n = n0 + rowb;
            bool ok = n < N;
            float s = yv[0][r] + yv[1][r] + yv[2][r] + yv[3][r];
#pragma unroll
            for (int off = 1; off < 16; off <<= 1) s += __shfl_xor(s, off, 64);
            float mu = s * (1.f / C);
            float d0 = yv[0][r] - mu, d1 = yv[1][r] - mu;
            float d2 = yv[2][r] - mu, d3 = yv[3][r] - mu;
            float vs = d0 * d0 + d1 * d1 + d2 * d2 + d3 * d3;
#pragma unroll
            for (int off = 1; off < 16; off <<= 1) vs += __shfl_xor(vs, off, 64);
            float rs = rsqrtf(vs * (1.f / C) + LN_EPS);
            float dd[4] = {d0, d1, d2, d3};
#pragma unroll
            for (int ct = 0; ct < 4; ct++) {
                float o = dd[ct] * rs * gc[ct] + bc[ct];
                if (ok) xout[(size_t)n * C + ct * 16 + lr] = o;
                int byte = (rowb * 128 + (ct * 16 + lr) * 2) ^ ((rowb & 7) << 4);
                *(unsigned short*)((char*)hls + byte) = ok ? f2bf(o) : 0;
            }
        }
    }
    __syncthreads();

    // ---- GEMM phase: xh = y @ Wg(next layer) + score epilogue ----
    {
        bf16x8 bfr[4][2];
        float as[4], ad[4];
#pragma unroll
        for (int ct = 0; ct < 4; ct++) {
            int colg = w * 64 + ct * 16 + lr;
#pragma unroll
            for (int ks = 0; ks < 2; ks++)
                bfr[ct][ks] = *reinterpret_cast<const bf16x8*>(Wgt2 + colg * C + ks * 32 + lk);
            as[ct] = a_src2[w * C + ct * 16 + lr];
            ad[ct] = a_dst2[w * C + ct * 16 + lr];
        }
#pragma unroll
        for (int rt = 0; rt < 4; rt++) {
            int arowb = rt * 16 + lr;
            int aswz = (arowb & 7) << 4;
            bf16x8 ga0 = *(bf16x8*)((char*)hls + ((arowb * 128 + q * 16) ^ aswz));
            bf16x8 ga1 = *(bf16x8*)((char*)hls + ((arowb * 128 + 64 + q * 16) ^ aswz));
            f32x4 acc[4];
#pragma unroll
            for (int ct = 0; ct < 4; ct++) {
                acc[ct] = (f32x4){0.f, 0.f, 0.f, 0.f};
                acc[ct] = __builtin_amdgcn_mfma_f32_16x16x32_bf16(ga0, bfr[ct][0], acc[ct], 0, 0, 0);
                acc[ct] = __builtin_amdgcn_mfma_f32_16x16x32_bf16(ga1, bfr[ct][1], acc[ct], 0, 0, 0);
            }
            int rowl = rt * 16 + q * 4;
#pragma unroll
            for (int ct = 0; ct < 4; ct++) {
                int cb = (w * 64 + ct * 16 + lr) * 2;
#pragma unroll
                for (int r = 0; r < 4; r++)
                    *(unsigned short*)(tile + (rowl + r) * LDSP + cb) = f2bf(acc[ct][r]);
            }
#pragma unroll
            for (int r = 0; r < 4; r++) {
                float ps = acc[0][r] * as[0] + acc[1][r] * as[1]
                         + acc[2][r] * as[2] + acc[3][r] * as[3];
                float pd = acc[0][r] * ad[0] + acc[1][r] * ad[1]
                         + acc[2][r] * ad[2] + acc[3][r] * ad[3];
#pragma unroll
                for (int off = 1; off < 16; off <<= 1) {
                    ps += __shfl_xor(ps, off, 64);
                    pd += __shfl_xor(pd, off, 64);
                }
                if (lr == 0) {
                    int n = n0 + rowl + r;  // < Npad
                    s_src[(size_t)n * H + w] = ps;
                    s_dst[(size_t)n * H + w] = pd;
                }
            }
        }
    }
    __syncthreads();
#pragma unroll
    for (int it = 0; it < 8; it++) {
        int off = threadIdx.x * 16 + it * 4096;
        int row = off >> 9;
        int cin = off & 511;
        uint4 v = *(const uint4*)(tile + row * LDSP + cin);
        *(uint4*)((char*)xh + (size_t)(n0 + row) * 512 + cin) = v;
    }
}

extern "C" void kernel_launch(void* const* d_in, const int* in_sizes, int n_in,
                              void* d_out, int out_size, void* d_ws, size_t ws_size,
                              hipStream_t stream) {
    const float* x        = (const float*)d_in[0];
    const int*   ei       = (const int*)d_in[1];
    const float* Wg       = (const float*)d_in[2];
    const float* a_src    = (const float*)d_in[3];
    const float* a_dst    = (const float*)d_in[4];
    const float* att_bias = (const float*)d_in[5];
    const float* ln1_g    = (const float*)d_in[6];
    const float* ln1_b    = (const float*)d_in[7];
    const float* W1       = (const float*)d_in[8];
    const float* b1       = (const float*)d_in[9];
    const float* W2       = (const float*)d_in[10];
    const float* b2       = (const float*)d_in[11];
    const float* ln2_g    = (const float*)d_in[12];
    const float* ln2_b    = (const float*)d_in[13];
    float* xout = (float*)d_out;

    int N = in_sizes[0] / C;
    int E = in_sizes[1] / 2;
    int Etot = E + N;
    int L = in_sizes[2] / (C * HC);
    int nb = (N + 255) / 256;
    int Npad = (N + 63) & ~63;

    char* p = (char*)d_ws;
    auto alloc = [&](size_t bytes) { void* r = (void*)p; p += (bytes + 255) & ~(size_t)255; return r; };
    float* s_src = (float*)alloc((size_t)Npad * H * 4);
    float* s_dst = (float*)alloc((size_t)Npad * H * 4);
    int* rowptr  = (int*)alloc((size_t)(N + 1) * 4);
    int* col     = (int*)alloc((size_t)Etot * 4);
    int* counts  = (int*)alloc((size_t)N * 4);
    int* tmp     = (int*)alloc((size_t)N * 4);
    int* bsum    = (int*)alloc((size_t)nb * 4);
    unsigned short* xb  = (unsigned short*)alloc((size_t)Npad * C * 2);
    unsigned short* x1b = (unsigned short*)alloc((size_t)Npad * C * 2);
    unsigned short* Wgt = (unsigned short*)alloc((size_t)L * HC * C * 2);
    unsigned short* W1t = (unsigned short*)alloc((size_t)L * C * C * 2);
    unsigned short* W2t = (unsigned short*)alloc((size_t)L * C * C * 2);
    unsigned short* xh  = (unsigned short*)alloc((size_t)Npad * HC * 2);

    // ---- CSR build (graph identical across layers) ----
    k_zero<<<256, 256, 0, stream>>>(counts, N);
    k_count<<<(Etot + 255) / 256, 256, 0, stream>>>(ei, counts, E, Etot);
    k_scan1<<<nb, 256, 0, stream>>>(counts, tmp, bsum, N);
    k_scan2<<<1, 256, 0, stream>>>(bsum, nb);
    k_scan3<<<nb, 256, 0, stream>>>(tmp, bsum, rowptr, counts, N);
    k_fill<<<(Etot + 255) / 256, 256, 0, stream>>>(ei, rowptr, counts, col, E, Etot);
    k_prep_x<<<2048, 256, 0, stream>>>((const float4*)x, (ushort4*)xb,
                                       N * C / 4, Npad * C / 4);
    {
        int tot = L * C * HC + L * C * C;
        k_prep_weights<<<(tot + 255) / 256, 256, 0, stream>>>(Wg, W1, W2, Wgt, W1t, W2t, L);
    }

    for (int l = 0; l < L; l++) {
        const float* xin = (l == 0) ? x : xout;
        if (l == 0)
            k_gemm_mfma<<<Npad / 64, 256, 0, stream>>>(
                xb, Wgt, a_src, a_dst, xh, s_src, s_dst, N);
        k_gat_node<<<(N + 3) / 4, 256, 0, stream>>>(
            rowptr, col, s_src, s_dst, xh, xin,
            att_bias + l * C, ln1_g + l * C, ln1_b + l * C, x1b, N);
        if (l < L - 1)
            k_ffn_gemm<<<Npad / 64, 256, 0, stream>>>(
                x1b, W1t + (size_t)l * C * C, W2t + (size_t)l * C * C,
                b1 + l * C, b2 + l * C, ln2_g + l * C, ln2_b + l * C,
                Wgt + (size_t)(l + 1) * HC * C,
                a_src + (size_t)(l + 1) * H * C, a_dst + (size_t)(l + 1) * H * C,
                xout, xh, s_src, s_dst, N);
        else
            k_ffn_mfma<<<Npad / 64, 256, 0, stream>>>(
                x1b, W1t + (size_t)l * C * C, W2t + (size_t)l * C * C,
                b1 + l * C, b2 + l * C, ln2_g + l * C, ln2_b + l * C, xout, N);
    }
}

// Round 20
// 209.926 us; speedup vs baseline: 1.0167x; 1.0167x over previous
//
#include <hip/hip_runtime.h>
#include <hip/hip_bf16.h>
#include <float.h>

#define C 64
#define H 4
#define HC 256
#define NEG_SLOPE 0.2f
#define EPS_SEG 1e-16f
#define LN_EPS 1e-5f
#define LDSP 528  // LDS tile pitch: 512B row + 16B bank-spread pad

typedef __attribute__((ext_vector_type(8))) short bf16x8;
typedef __attribute__((ext_vector_type(4))) float f32x4;

__device__ __forceinline__ float warp_sum(float v) {
#pragma unroll
    for (int m = 32; m >= 1; m >>= 1) v += __shfl_xor(v, m, 64);
    return v;
}

__device__ __forceinline__ unsigned short f2bf(float f) {
    unsigned int u = __float_as_uint(f);
    return (unsigned short)((u + 0x7FFF + ((u >> 16) & 1)) >> 16);  // RNE
}

// ---------------- CSR build (once per call; graph is layer-invariant) -------

__global__ void k_zero(int* __restrict__ a, int n) {
    int i = blockIdx.x * blockDim.x + threadIdx.x;
    int stride = gridDim.x * blockDim.x;
    for (int j = i; j < n; j += stride) a[j] = 0;
}

__global__ void k_count(const int* __restrict__ ei, int* __restrict__ counts,
                        int E, int Etot) {
    int eid = blockIdx.x * blockDim.x + threadIdx.x;
    if (eid >= Etot) return;
    int d = (eid < E) ? ei[E + eid] : eid - E;
    atomicAdd(&counts[d], 1);
}

__global__ __launch_bounds__(256) void k_scan1(const int* __restrict__ counts,
                                               int* __restrict__ tmp,
                                               int* __restrict__ bsum, int N) {
    __shared__ int sm[256];
    int t = threadIdx.x;
    int i = blockIdx.x * 256 + t;
    sm[t] = (i < N) ? counts[i] : 0;
    __syncthreads();
    for (int off = 1; off < 256; off <<= 1) {
        int add = (t >= off) ? sm[t - off] : 0;
        __syncthreads();
        sm[t] += add;
        __syncthreads();
    }
    if (i < N) tmp[i] = sm[t];
    if (t == 255) bsum[blockIdx.x] = sm[255];
}

__global__ __launch_bounds__(256) void k_scan2(int* __restrict__ bsum, int nb) {
    __shared__ int sm[256];
    int t = threadIdx.x;
    sm[t] = (t < nb) ? bsum[t] : 0;
    __syncthreads();
    for (int off = 1; off < 256; off <<= 1) {
        int add = (t >= off) ? sm[t - off] : 0;
        __syncthreads();
        sm[t] += add;
        __syncthreads();
    }
    if (t < nb) bsum[t] = (t > 0) ? sm[t - 1] : 0;  // exclusive
}

__global__ __launch_bounds__(256) void k_scan3(const int* __restrict__ tmp,
                                               const int* __restrict__ boff,
                                               int* __restrict__ rowptr,
                                               int* __restrict__ cursor, int N) {
    int i = blockIdx.x * 256 + threadIdx.x;
    if (i < N) {
        rowptr[i + 1] = tmp[i] + boff[blockIdx.x];
        cursor[i] = 0;
    }
    if (i == 0) rowptr[0] = 0;
}

__global__ void k_fill(const int* __restrict__ ei, const int* __restrict__ rowptr,
                       int* __restrict__ cursor, int* __restrict__ col,
                       int E, int Etot) {
    int eid = blockIdx.x * blockDim.x + threadIdx.x;
    if (eid >= Etot) return;
    int s, d;
    if (eid < E) { s = ei[eid]; d = ei[E + eid]; } else { s = d = eid - E; }
    int pos = rowptr[d] + atomicAdd(&cursor[d], 1);
    col[pos] = s;
}

// ---------------- per-layer kernels ----------------------------------------

// f32 [N][C] -> bf16 [Npad][C] (pad rows zeroed); layer-0 only.
__global__ void k_prep_x(const float4* __restrict__ xin, ushort4* __restrict__ xb,
                         int n4, int npad4) {
    int i = blockIdx.x * blockDim.x + threadIdx.x;
    int st = gridDim.x * blockDim.x;
    for (int j = i; j < npad4; j += st) {
        ushort4 o;
        if (j < n4) {
            float4 v = xin[j];
            o.x = f2bf(v.x); o.y = f2bf(v.y); o.z = f2bf(v.z); o.w = f2bf(v.w);
        } else {
            o.x = o.y = o.z = o.w = 0;
        }
        xb[j] = o;
    }
}

// All weight transposes (Wg + W1 + W2, both layers) in one launch.
__global__ void k_prep_weights(const float* __restrict__ Wg,
                               const float* __restrict__ W1, const float* __restrict__ W2,
                               unsigned short* __restrict__ Wgt,
                               unsigned short* __restrict__ W1t,
                               unsigned short* __restrict__ W2t, int L) {
    int i = blockIdx.x * 256 + threadIdx.x;
    int nWg = L * C * HC;
    int nW = L * C * C;
    if (i < nWg) {
        int l = i / (C * HC);
        int r = i - l * C * HC;
        int n = r >> 6, k = r & 63;
        Wgt[(size_t)l * HC * C + n * C + k] = f2bf(Wg[(size_t)l * C * HC + k * HC + n]);
    } else if (i < nWg + nW) {
        int j = i - nWg;
        int l = j / (C * C);
        int r = j - l * C * C;
        int n = r >> 6, k = r & 63;
        W1t[(size_t)l * C * C + n * C + k] = f2bf(W1[(size_t)l * C * C + k * C + n]);
        W2t[(size_t)l * C * C + n * C + k] = f2bf(W2[(size_t)l * C * C + k * C + n]);
    }
}

// xh = xb @ Wg via MFMA (layer-0 only). D staged through LDS for coalesced
// dwordx4 xh stores. Scores to dense Npad-sized s_src/s_dst (L2-resident).
__global__ __launch_bounds__(256) void k_gemm_mfma(
    const unsigned short* __restrict__ xb, const unsigned short* __restrict__ Wgt,
    const float* __restrict__ a_src, const float* __restrict__ a_dst,
    unsigned short* __restrict__ xh, float* __restrict__ s_src,
    float* __restrict__ s_dst, int N)
{
    __shared__ char tile[64 * LDSP];  // 33 KB
    int w = threadIdx.x >> 6, l = threadIdx.x & 63;
    int n0 = blockIdx.x * 64;
    int lr = l & 15, q = l >> 4, lk = q * 8;
    bf16x8 bfr[4][2];
    float as[4], ad[4];
#pragma unroll
    for (int ct = 0; ct < 4; ct++) {
        int colg = w * 64 + ct * 16 + lr;
#pragma unroll
        for (int ks = 0; ks < 2; ks++)
            bfr[ct][ks] = *reinterpret_cast<const bf16x8*>(Wgt + colg * C + ks * 32 + lk);
        as[ct] = a_src[w * C + ct * 16 + lr];
        ad[ct] = a_dst[w * C + ct * 16 + lr];
    }
#pragma unroll
    for (int rt = 0; rt < 4; rt++) {
        const unsigned short* arow = xb + (size_t)(n0 + rt * 16 + lr) * C + lk;
        bf16x8 a0 = *reinterpret_cast<const bf16x8*>(arow);
        bf16x8 a1 = *reinterpret_cast<const bf16x8*>(arow + 32);
        f32x4 acc[4];
#pragma unroll
        for (int ct = 0; ct < 4; ct++) {
            acc[ct] = (f32x4){0.f, 0.f, 0.f, 0.f};
            acc[ct] = __builtin_amdgcn_mfma_f32_16x16x32_bf16(a0, bfr[ct][0], acc[ct], 0, 0, 0);
            acc[ct] = __builtin_amdgcn_mfma_f32_16x16x32_bf16(a1, bfr[ct][1], acc[ct], 0, 0, 0);
        }
        int rowl = rt * 16 + q * 4;
#pragma unroll
        for (int ct = 0; ct < 4; ct++) {
            int cb = (w * 64 + ct * 16 + lr) * 2;
#pragma unroll
            for (int r = 0; r < 4; r++)
                *(unsigned short*)(tile + (rowl + r) * LDSP + cb) = f2bf(acc[ct][r]);
        }
#pragma unroll
        for (int r = 0; r < 4; r++) {
            float ps = acc[0][r] * as[0] + acc[1][r] * as[1]
                     + acc[2][r] * as[2] + acc[3][r] * as[3];
            float pd = acc[0][r] * ad[0] + acc[1][r] * ad[1]
                     + acc[2][r] * ad[2] + acc[3][r] * ad[3];
#pragma unroll
            for (int off = 1; off < 16; off <<= 1) {
                ps += __shfl_xor(ps, off, 64);
                pd += __shfl_xor(pd, off, 64);
            }
            if (lr == 0) {
                int n = n0 + rowl + r;  // < Npad; buffers Npad-sized
                s_src[(size_t)n * H + w] = ps;
                s_dst[(size_t)n * H + w] = pd;
            }
        }
    }
    __syncthreads();
#pragma unroll
    for (int it = 0; it < 8; it++) {
        int off = threadIdx.x * 16 + it * 4096;
        int row = off >> 9;
        int cin = off & 511;
        uint4 v = *(const uint4*)(tile + row * LDSP + cin);
        *(uint4*)((char*)xh + (size_t)(n0 + row) * 512 + cin) = v;
    }
}

// One wave per destination node; lane l = h*16+gq. MLP-4 chunk loop +
// 3-slot tail; dense 512B xh rows; scores from compact L2-resident arrays.
__global__ __launch_bounds__(256) void k_gat_node(
    const int* __restrict__ rowptr, const int* __restrict__ col,
    const float* __restrict__ s_src, const float* __restrict__ s_dst,
    const unsigned short* __restrict__ xh,
    const float* __restrict__ x_in, const float* __restrict__ bias,
    const float* __restrict__ g, const float* __restrict__ b,
    float* __restrict__ x1, unsigned short* __restrict__ x1b, int N)
{
    int n = (blockIdx.x * blockDim.x + threadIdx.x) >> 6;
    int l = threadIdx.x & 63;
    int h = l >> 4, gq = l & 15;
    if (n >= N) return;
    int r0 = rowptr[n], r1 = rowptr[n + 1];

    float4 xi = *(const float4*)(x_in + (size_t)n * C + gq * 4);
    float4 bia = *(const float4*)(bias + gq * 4);
    float sdh = s_dst[n * H + h];

    const char* xbase = (const char*)xh;
    int laneoff = h * 128 + gq * 8;

    float a0 = 0.f, a1 = 0.f, a2 = 0.f, a3 = 0.f, z = 0.f;

    int j = r0;
    for (; j + 4 <= r1; j += 4) {
        int s0 = col[j], s1 = col[j + 1], s2 = col[j + 2], s3 = col[j + 3];
        uint2 v0 = *(const uint2*)(xbase + (size_t)s0 * 512 + laneoff);
        uint2 v1 = *(const uint2*)(xbase + (size_t)s1 * 512 + laneoff);
        uint2 v2 = *(const uint2*)(xbase + (size_t)s2 * 512 + laneoff);
        uint2 v3 = *(const uint2*)(xbase + (size_t)s3 * 512 + laneoff);
        float e0 = s_src[s0 * H + h] + sdh;
        float e1 = s_src[s1 * H + h] + sdh;
        float e2 = s_src[s2 * H + h] + sdh;
        float e3 = s_src[s3 * H + h] + sdh;
        float w0 = __expf(fmaxf(e0, NEG_SLOPE * e0));
        float w1 = __expf(fmaxf(e1, NEG_SLOPE * e1));
        float w2 = __expf(fmaxf(e2, NEG_SLOPE * e2));
        float w3 = __expf(fmaxf(e3, NEG_SLOPE * e3));
        a0 += w0 * __uint_as_float(v0.x << 16);
        a1 += w0 * __uint_as_float(v0.x & 0xFFFF0000u);
        a2 += w0 * __uint_as_float(v0.y << 16);
        a3 += w0 * __uint_as_float(v0.y & 0xFFFF0000u);
        a0 += w1 * __uint_as_float(v1.x << 16);
        a1 += w1 * __uint_as_float(v1.x & 0xFFFF0000u);
        a2 += w1 * __uint_as_float(v1.y << 16);
        a3 += w1 * __uint_as_float(v1.y & 0xFFFF0000u);
        a0 += w2 * __uint_as_float(v2.x << 16);
        a1 += w2 * __uint_as_float(v2.x & 0xFFFF0000u);
        a2 += w2 * __uint_as_float(v2.y << 16);
        a3 += w2 * __uint_as_float(v2.y & 0xFFFF0000u);
        a0 += w3 * __uint_as_float(v3.x << 16);
        a1 += w3 * __uint_as_float(v3.x & 0xFFFF0000u);
        a2 += w3 * __uint_as_float(v3.y << 16);
        a3 += w3 * __uint_as_float(v3.y & 0xFFFF0000u);
        z += w0 + w1 + w2 + w3;
    }
    {   // tail (0-3 edges): masked weights, wave-uniform predication
        int t = r1 - j;
        int s0 = 0, s1 = 0, s2 = 0;
        if (t > 0) s0 = col[j];
        if (t > 1) s1 = col[j + 1];
        if (t > 2) s2 = col[j + 2];
        uint2 v0 = {0, 0}, v1 = {0, 0}, v2 = {0, 0};
        float e0 = 0.f, e1 = 0.f, e2 = 0.f;
        if (t > 0) { v0 = *(const uint2*)(xbase + (size_t)s0 * 512 + laneoff); e0 = s_src[s0 * H + h] + sdh; }
        if (t > 1) { v1 = *(const uint2*)(xbase + (size_t)s1 * 512 + laneoff); e1 = s_src[s1 * H + h] + sdh; }
        if (t > 2) { v2 = *(const uint2*)(xbase + (size_t)s2 * 512 + laneoff); e2 = s_src[s2 * H + h] + sdh; }
        float w0 = (t > 0) ? __expf(fmaxf(e0, NEG_SLOPE * e0)) : 0.f;
        float w1 = (t > 1) ? __expf(fmaxf(e1, NEG_SLOPE * e1)) : 0.f;
        float w2 = (t > 2) ? __expf(fmaxf(e2, NEG_SLOPE * e2)) : 0.f;
        a0 += w0 * __uint_as_float(v0.x << 16);
        a1 += w0 * __uint_as_float(v0.x & 0xFFFF0000u);
        a2 += w0 * __uint_as_float(v0.y << 16);
        a3 += w0 * __uint_as_float(v0.y & 0xFFFF0000u);
        a0 += w1 * __uint_as_float(v1.x << 16);
        a1 += w1 * __uint_as_float(v1.x & 0xFFFF0000u);
        a2 += w1 * __uint_as_float(v1.y << 16);
        a3 += w1 * __uint_as_float(v1.y & 0xFFFF0000u);
        a0 += w2 * __uint_as_float(v2.x << 16);
        a1 += w2 * __uint_as_float(v2.x & 0xFFFF0000u);
        a2 += w2 * __uint_as_float(v2.y << 16);
        a3 += w2 * __uint_as_float(v2.y & 0xFFFF0000u);
        z += w0 + w1 + w2;
    }

    float inv = 0.25f / (z + EPS_SEG);
    a0 *= inv; a1 *= inv; a2 *= inv; a3 *= inv;
#pragma unroll
    for (int off = 16; off <= 32; off <<= 1) {
        a0 += __shfl_xor(a0, off, 64);
        a1 += __shfl_xor(a1, off, 64);
        a2 += __shfl_xor(a2, off, 64);
        a3 += __shfl_xor(a3, off, 64);
    }
    float y0 = xi.x + a0 + bia.x;
    float y1 = xi.y + a1 + bia.y;
    float y2 = xi.z + a2 + bia.z;
    float y3 = xi.w + a3 + bia.w;
    float mu = warp_sum(y0 + y1 + y2 + y3) * (1.f / (C * 4));
    float d0 = y0 - mu, d1 = y1 - mu, d2 = y2 - mu, d3 = y3 - mu;
    float var = warp_sum(d0 * d0 + d1 * d1 + d2 * d2 + d3 * d3) * (1.f / (C * 4));
    float rs = rsqrtf(var + LN_EPS);
    if (h == 0) {
        float4 gg = *(const float4*)(g + gq * 4);
        float4 bb = *(const float4*)(b + gq * 4);
        float4 o;
        o.x = d0 * rs * gg.x + bb.x;
        o.y = d1 * rs * gg.y + bb.y;
        o.z = d2 * rs * gg.z + bb.z;
        o.w = d3 * rs * gg.w + bb.w;
        *(float4*)(x1 + (size_t)n * C + gq * 4) = o;
        ushort4 ob;
        ob.x = f2bf(o.x); ob.y = f2bf(o.y); ob.z = f2bf(o.z); ob.w = f2bf(o.w);
        *(ushort4*)(x1b + (size_t)n * C + gq * 4) = ob;
    }
}

// FFN + residual + LN (standalone; LAST layer).
__global__ __launch_bounds__(256) void k_ffn_mfma(
    const float* __restrict__ x1f, const unsigned short* __restrict__ x1b,
    const unsigned short* __restrict__ W1t, const unsigned short* __restrict__ W2t,
    const float* __restrict__ b1, const float* __restrict__ b2,
    const float* __restrict__ g, const float* __restrict__ b,
    float* __restrict__ xout, int N)
{
    __shared__ unsigned short hls[64 * 64];  // 8 KB
    int w = threadIdx.x >> 6, l = threadIdx.x & 63;
    int lr = l & 15, q = l >> 4, lk = q * 8;
    int n0 = blockIdx.x * 64;

    {
        bf16x8 bf[4][2];
#pragma unroll
        for (int ct = 0; ct < 4; ct++)
#pragma unroll
            for (int ks = 0; ks < 2; ks++)
                bf[ct][ks] = *reinterpret_cast<const bf16x8*>(
                    W1t + (ct * 16 + lr) * C + ks * 32 + lk);
        const unsigned short* arow = x1b + (size_t)(n0 + w * 16 + lr) * C + lk;
        bf16x8 a0 = *reinterpret_cast<const bf16x8*>(arow);
        bf16x8 a1 = *reinterpret_cast<const bf16x8*>(arow + 32);
        f32x4 acc[4];
#pragma unroll
        for (int ct = 0; ct < 4; ct++) {
            acc[ct] = (f32x4){0.f, 0.f, 0.f, 0.f};
            acc[ct] = __builtin_amdgcn_mfma_f32_16x16x32_bf16(a0, bf[ct][0], acc[ct], 0, 0, 0);
            acc[ct] = __builtin_amdgcn_mfma_f32_16x16x32_bf16(a1, bf[ct][1], acc[ct], 0, 0, 0);
        }
#pragma unroll
        for (int ct = 0; ct < 4; ct++) {
            float bc = b1[ct * 16 + lr];
#pragma unroll
            for (int r = 0; r < 4; r++) {
                float v = fmaxf(acc[ct][r] + bc, 0.f);
                int rowb = w * 16 + q * 4 + r;
                int byte = (rowb * 128 + (ct * 16 + lr) * 2) ^ ((rowb & 7) << 4);
                *(unsigned short*)((char*)hls + byte) = f2bf(v);
            }
        }
    }
    __syncthreads();

    bf16x8 bf[4][2];
#pragma unroll
    for (int ct = 0; ct < 4; ct++)
#pragma unroll
        for (int ks = 0; ks < 2; ks++)
            bf[ct][ks] = *reinterpret_cast<const bf16x8*>(
                W2t + (ct * 16 + lr) * C + ks * 32 + lk);
    bf16x8 h0, h1;
    {
        int rowb = w * 16 + lr;
        int swz = (rowb & 7) << 4;
        h0 = *(bf16x8*)((char*)hls + ((rowb * 128 + q * 16) ^ swz));
        h1 = *(bf16x8*)((char*)hls + ((rowb * 128 + 64 + q * 16) ^ swz));
    }
    f32x4 acc[4];
#pragma unroll
    for (int ct = 0; ct < 4; ct++) {
        acc[ct] = (f32x4){0.f, 0.f, 0.f, 0.f};
        acc[ct] = __builtin_amdgcn_mfma_f32_16x16x32_bf16(h0, bf[ct][0], acc[ct], 0, 0, 0);
        acc[ct] = __builtin_amdgcn_mfma_f32_16x16x32_bf16(h1, bf[ct][1], acc[ct], 0, 0, 0);
    }

    float b2c[4], gc[4], bc[4];
#pragma unroll
    for (int ct = 0; ct < 4; ct++) {
        int cg = ct * 16 + lr;
        b2c[ct] = b2[cg]; gc[ct] = g[cg]; bc[ct] = b[cg];
    }
    float yv[4][4];
#pragma unroll
    for (int r = 0; r < 4; r++) {
        int n = n0 + w * 16 + q * 4 + r;
        bool ok = n < N;
#pragma unroll
        for (int ct = 0; ct < 4; ct++) {
            float xr = ok ? x1f[(size_t)n * C + ct * 16 + lr] : 0.f;
            yv[ct][r] = acc[ct][r] + b2c[ct] + xr;
        }
    }
#pragma unroll
    for (int r = 0; r < 4; r++) {
        int n = n0 + w * 16 + q * 4 + r;
        float s = yv[0][r] + yv[1][r] + yv[2][r] + yv[3][r];
#pragma unroll
        for (int off = 1; off < 16; off <<= 1) s += __shfl_xor(s, off, 64);
        float mu = s * (1.f / C);
        float d0 = yv[0][r] - mu, d1 = yv[1][r] - mu;
        float d2 = yv[2][r] - mu, d3 = yv[3][r] - mu;
        float vs = d0 * d0 + d1 * d1 + d2 * d2 + d3 * d3;
#pragma unroll
        for (int off = 1; off < 16; off <<= 1) vs += __shfl_xor(vs, off, 64);
        float rs = rsqrtf(vs * (1.f / C) + LN_EPS);
        if (n < N) {
            float dd[4] = {d0, d1, d2, d3};
#pragma unroll
            for (int ct = 0; ct < 4; ct++) {
                float o = dd[ct] * rs * gc[ct] + bc[ct];
                xout[(size_t)n * C + ct * 16 + lr] = o;
            }
        }
    }
}

// FUSED: FFN(layer l) + GEMM(layer l+1). After LN, the bf16 y-tile stays in
// LDS (hls reused after a barrier) and feeds the next layer's xh = y @ Wg
// MFMA + score epilogue directly -- kills the standalone gemm dispatch and
// the xb global round-trip.
__global__ __launch_bounds__(256) void k_ffn_gemm(
    const float* __restrict__ x1f, const unsigned short* __restrict__ x1b,
    const unsigned short* __restrict__ W1t, const unsigned short* __restrict__ W2t,
    const float* __restrict__ b1, const float* __restrict__ b2,
    const float* __restrict__ g, const float* __restrict__ b,
    const unsigned short* __restrict__ Wgt2,
    const float* __restrict__ a_src2, const float* __restrict__ a_dst2,
    float* __restrict__ xout, unsigned short* __restrict__ xh,
    float* __restrict__ s_src, float* __restrict__ s_dst, int N)
{
    __shared__ char tile[64 * LDSP];         // 33 KB xh staging
    __shared__ unsigned short hls[64 * 64];  // 8 KB: h-tile, then y-tile
    int w = threadIdx.x >> 6, l = threadIdx.x & 63;
    int lr = l & 15, q = l >> 4, lk = q * 8;
    int n0 = blockIdx.x * 64;

    // ---- FFN phase 1: h = relu(x1 @ W1 + b1) -> hls ----
    {
        bf16x8 bf[4][2];
#pragma unroll
        for (int ct = 0; ct < 4; ct++)
#pragma unroll
            for (int ks = 0; ks < 2; ks++)
                bf[ct][ks] = *reinterpret_cast<const bf16x8*>(
                    W1t + (ct * 16 + lr) * C + ks * 32 + lk);
        const unsigned short* arow = x1b + (size_t)(n0 + w * 16 + lr) * C + lk;
        bf16x8 a0 = *reinterpret_cast<const bf16x8*>(arow);
        bf16x8 a1 = *reinterpret_cast<const bf16x8*>(arow + 32);
        f32x4 acc[4];
#pragma unroll
        for (int ct = 0; ct < 4; ct++) {
            acc[ct] = (f32x4){0.f, 0.f, 0.f, 0.f};
            acc[ct] = __builtin_amdgcn_mfma_f32_16x16x32_bf16(a0, bf[ct][0], acc[ct], 0, 0, 0);
            acc[ct] = __builtin_amdgcn_mfma_f32_16x16x32_bf16(a1, bf[ct][1], acc[ct], 0, 0, 0);
        }
#pragma unroll
        for (int ct = 0; ct < 4; ct++) {
            float bc = b1[ct * 16 + lr];
#pragma unroll
            for (int r = 0; r < 4; r++) {
                float v = fmaxf(acc[ct][r] + bc, 0.f);
                int rowb = w * 16 + q * 4 + r;
                int byte = (rowb * 128 + (ct * 16 + lr) * 2) ^ ((rowb & 7) << 4);
                *(unsigned short*)((char*)hls + byte) = f2bf(v);
            }
        }
    }
    __syncthreads();

    // ---- FFN phase 2: y = h @ W2 + b2 + x1, LN -> xout f32 + y bf16 in hls --
    {
        bf16x8 bf[4][2];
#pragma unroll
        for (int ct = 0; ct < 4; ct++)
#pragma unroll
            for (int ks = 0; ks < 2; ks++)
                bf[ct][ks] = *reinterpret_cast<const bf16x8*>(
                    W2t + (ct * 16 + lr) * C + ks * 32 + lk);
        bf16x8 h0, h1;
        {
            int rowb = w * 16 + lr;
            int swz = (rowb & 7) << 4;
            h0 = *(bf16x8*)((char*)hls + ((rowb * 128 + q * 16) ^ swz));
            h1 = *(bf16x8*)((char*)hls + ((rowb * 128 + 64 + q * 16) ^ swz));
        }
        __syncthreads();  // all h reads complete before hls is overwritten
        f32x4 acc[4];
#pragma unroll
        for (int ct = 0; ct < 4; ct++) {
            acc[ct] = (f32x4){0.f, 0.f, 0.f, 0.f};
            acc[ct] = __builtin_amdgcn_mfma_f32_16x16x32_bf16(h0, bf[ct][0], acc[ct], 0, 0, 0);
            acc[ct] = __builtin_amdgcn_mfma_f32_16x16x32_bf16(h1, bf[ct][1], acc[ct], 0, 0, 0);
        }
        float b2c[4], gc[4], bc[4];
#pragma unroll
        for (int ct = 0; ct < 4; ct++) {
            int cg = ct * 16 + lr;
            b2c[ct] = b2[cg]; gc[ct] = g[cg]; bc[ct] = b[cg];
        }
        float yv[4][4];
#pragma unroll
        for (int r = 0; r < 4; r++) {
            int n = n0 + w * 16 + q * 4 + r;
            bool ok = n < N;
#pragma unroll
            for (int ct = 0; ct < 4; ct++) {
                float xr = ok ? x1f[(size_t)n * C + ct * 16 + lr] : 0.f;
                yv[ct][r] = acc[ct][r] + b2c[ct] + xr;
            }
        }
#pragma unroll
        for (int r = 0; r < 4; r++) {
            int rowb = w * 16 + q * 4 + r;
            int n = n0 + rowb;
            bool ok = n < N;
            float s = yv[0][r] + yv[1][r] + yv[2][r] + yv[3][r];
#pragma unroll
            for (int off = 1; off < 16; off <<= 1) s += __shfl_xor(s, off, 64);
            float mu = s * (1.f / C);
            float d0 = yv[0][r] - mu, d1 = yv[1][r] - mu;
            float d2 = yv[2][r] - mu, d3 = yv[3][r] - mu;
            float vs = d0 * d0 + d1 * d1 + d2 * d2 + d3 * d3;
#pragma unroll
            for (int off = 1; off < 16; off <<= 1) vs += __shfl_xor(vs, off, 64);
            float rs = rsqrtf(vs * (1.f / C) + LN_EPS);
            float dd[4] = {d0, d1, d2, d3};
#pragma unroll
            for (int ct = 0; ct < 4; ct++) {
                float o = dd[ct] * rs * gc[ct] + bc[ct];
                if (ok) xout[(size_t)n * C + ct * 16 + lr] = o;
                int byte = (rowb * 128 + (ct * 16 + lr) * 2) ^ ((rowb & 7) << 4);
                *(unsigned short*)((char*)hls + byte) = ok ? f2bf(o) : 0;
            }
        }
    }
    __syncthreads();

    // ---- GEMM phase: xh = y @ Wg(next layer) + score epilogue ----
    {
        bf16x8 bfr[4][2];
        float as[4], ad[4];
#pragma unroll
        for (int ct = 0; ct < 4; ct++) {
            int colg = w * 64 + ct * 16 + lr;
#pragma unroll
            for (int ks = 0; ks < 2; ks++)
                bfr[ct][ks] = *reinterpret_cast<const bf16x8*>(Wgt2 + colg * C + ks * 32 + lk);
            as[ct] = a_src2[w * C + ct * 16 + lr];
            ad[ct] = a_dst2[w * C + ct * 16 + lr];
        }
#pragma unroll
        for (int rt = 0; rt < 4; rt++) {
            int arowb = rt * 16 + lr;
            int aswz = (arowb & 7) << 4;
            bf16x8 ga0 = *(bf16x8*)((char*)hls + ((arowb * 128 + q * 16) ^ aswz));
            bf16x8 ga1 = *(bf16x8*)((char*)hls + ((arowb * 128 + 64 + q * 16) ^ aswz));
            f32x4 acc[4];
#pragma unroll
            for (int ct = 0; ct < 4; ct++) {
                acc[ct] = (f32x4){0.f, 0.f, 0.f, 0.f};
                acc[ct] = __builtin_amdgcn_mfma_f32_16x16x32_bf16(ga0, bfr[ct][0], acc[ct], 0, 0, 0);
                acc[ct] = __builtin_amdgcn_mfma_f32_16x16x32_bf16(ga1, bfr[ct][1], acc[ct], 0, 0, 0);
            }
            int rowl = rt * 16 + q * 4;
#pragma unroll
            for (int ct = 0; ct < 4; ct++) {
                int cb = (w * 64 + ct * 16 + lr) * 2;
#pragma unroll
                for (int r = 0; r < 4; r++)
                    *(unsigned short*)(tile + (rowl + r) * LDSP + cb) = f2bf(acc[ct][r]);
            }
#pragma unroll
            for (int r = 0; r < 4; r++) {
                float ps = acc[0][r] * as[0] + acc[1][r] * as[1]
                         + acc[2][r] * as[2] + acc[3][r] * as[3];
                float pd = acc[0][r] * ad[0] + acc[1][r] * ad[1]
                         + acc[2][r] * ad[2] + acc[3][r] * ad[3];
#pragma unroll
                for (int off = 1; off < 16; off <<= 1) {
                    ps += __shfl_xor(ps, off, 64);
                    pd += __shfl_xor(pd, off, 64);
                }
                if (lr == 0) {
                    int n = n0 + rowl + r;  // < Npad
                    s_src[(size_t)n * H + w] = ps;
                    s_dst[(size_t)n * H + w] = pd;
                }
            }
        }
    }
    __syncthreads();
#pragma unroll
    for (int it = 0; it < 8; it++) {
        int off = threadIdx.x * 16 + it * 4096;
        int row = off >> 9;
        int cin = off & 511;
        uint4 v = *(const uint4*)(tile + row * LDSP + cin);
        *(uint4*)((char*)xh + (size_t)(n0 + row) * 512 + cin) = v;
    }
}

extern "C" void kernel_launch(void* const* d_in, const int* in_sizes, int n_in,
                              void* d_out, int out_size, void* d_ws, size_t ws_size,
                              hipStream_t stream) {
    const float* x        = (const float*)d_in[0];
    const int*   ei       = (const int*)d_in[1];
    const float* Wg       = (const float*)d_in[2];
    const float* a_src    = (const float*)d_in[3];
    const float* a_dst    = (const float*)d_in[4];
    const float* att_bias = (const float*)d_in[5];
    const float* ln1_g    = (const float*)d_in[6];
    const float* ln1_b    = (const float*)d_in[7];
    const float* W1       = (const float*)d_in[8];
    const float* b1       = (const float*)d_in[9];
    const float* W2       = (const float*)d_in[10];
    const float* b2       = (const float*)d_in[11];
    const float* ln2_g    = (const float*)d_in[12];
    const float* ln2_b    = (const float*)d_in[13];
    float* xout = (float*)d_out;

    int N = in_sizes[0] / C;
    int E = in_sizes[1] / 2;
    int Etot = E + N;
    int L = in_sizes[2] / (C * HC);
    int nb = (N + 255) / 256;
    int Npad = (N + 63) & ~63;

    char* p = (char*)d_ws;
    auto alloc = [&](size_t bytes) { void* r = (void*)p; p += (bytes + 255) & ~(size_t)255; return r; };
    float* s_src = (float*)alloc((size_t)Npad * H * 4);
    float* s_dst = (float*)alloc((size_t)Npad * H * 4);
    float* x1    = (float*)alloc((size_t)N * C * 4);
    int* rowptr  = (int*)alloc((size_t)(N + 1) * 4);
    int* col     = (int*)alloc((size_t)Etot * 4);
    int* counts  = (int*)alloc((size_t)N * 4);
    int* tmp     = (int*)alloc((size_t)N * 4);
    int* bsum    = (int*)alloc((size_t)nb * 4);
    unsigned short* xb  = (unsigned short*)alloc((size_t)Npad * C * 2);
    unsigned short* x1b = (unsigned short*)alloc((size_t)Npad * C * 2);
    unsigned short* Wgt = (unsigned short*)alloc((size_t)L * HC * C * 2);
    unsigned short* W1t = (unsigned short*)alloc((size_t)L * C * C * 2);
    unsigned short* W2t = (unsigned short*)alloc((size_t)L * C * C * 2);
    unsigned short* xh  = (unsigned short*)alloc((size_t)Npad * HC * 2);

    // ---- CSR build (graph identical across layers) ----
    k_zero<<<256, 256, 0, stream>>>(counts, N);
    k_count<<<(Etot + 255) / 256, 256, 0, stream>>>(ei, counts, E, Etot);
    k_scan1<<<nb, 256, 0, stream>>>(counts, tmp, bsum, N);
    k_scan2<<<1, 256, 0, stream>>>(bsum, nb);
    k_scan3<<<nb, 256, 0, stream>>>(tmp, bsum, rowptr, counts, N);
    k_fill<<<(Etot + 255) / 256, 256, 0, stream>>>(ei, rowptr, counts, col, E, Etot);
    k_prep_x<<<2048, 256, 0, stream>>>((const float4*)x, (ushort4*)xb,
                                       N * C / 4, Npad * C / 4);
    {
        int tot = L * C * HC + L * C * C;
        k_prep_weights<<<(tot + 255) / 256, 256, 0, stream>>>(Wg, W1, W2, Wgt, W1t, W2t, L);
    }

    for (int l = 0; l < L; l++) {
        const float* xin = (l == 0) ? x : xout;
        if (l == 0)
            k_gemm_mfma<<<Npad / 64, 256, 0, stream>>>(
                xb, Wgt, a_src, a_dst, xh, s_src, s_dst, N);
        k_gat_node<<<(N + 3) / 4, 256, 0, stream>>>(
            rowptr, col, s_src, s_dst, xh, xin,
            att_bias + l * C, ln1_g + l * C, ln1_b + l * C, x1, x1b, N);
        if (l < L - 1)
            k_ffn_gemm<<<Npad / 64, 256, 0, stream>>>(
                x1, x1b, W1t + (size_t)l * C * C, W2t + (size_t)l * C * C,
                b1 + l * C, b2 + l * C, ln2_g + l * C, ln2_b + l * C,
                Wgt + (size_t)(l + 1) * HC * C,
                a_src + (size_t)(l + 1) * H * C, a_dst + (size_t)(l + 1) * H * C,
                xout, xh, s_src, s_dst, N);
        else
            k_ffn_mfma<<<Npad / 64, 256, 0, stream>>>(
                x1, x1b, W1t + (size_t)l * C * C, W2t + (size_t)l * C * C,
                b1 + l * C, b2 + l * C, ln2_g + l * C, ln2_b + l * C, xout, N);
    }
}